// Round 6
// baseline (204.551 us; speedup 1.0000x reference)
//
#include <hip/hip_runtime.h>
#include <math.h>

#define BB   4
#define LL   2048
#define DM   256
#define DI   512
#define DSN  16
#define HIDN 512
#define NC2  32
#define CK2  64           // LL / NC2
#define ROWS (BB*LL)      // 8192

typedef __attribute__((ext_vector_type(8))) short s8v;   // 8 bf16 (4 VGPRs)
typedef __attribute__((ext_vector_type(4))) float f4v;   // 4 fp32 acc

__device__ __forceinline__ float sig_(float x) { return 1.f / (1.f + __expf(-x)); }
__device__ __forceinline__ float dot4(float4 a, float4 w, float acc) {
    return fmaf(a.x,w.x, fmaf(a.y,w.y, fmaf(a.z,w.z, fmaf(a.w,w.w, acc))));
}
__device__ __forceinline__ unsigned short rne_bf16(float f) {
    union { float f; unsigned u; } v; v.f = f;
    unsigned r = v.u + 0x7FFFu + ((v.u >> 16) & 1u);
    return (unsigned short)(r >> 16);
}
__device__ __forceinline__ float softplus_(float a) {
    return (a > 15.f) ? a : __logf(1.f + __expf(a));
}

// ---------------- K0: fp32 -> bf16 convert (x, W_in[0:512], W_xproj) ----------------
#define XQ  (ROWS*DM/4)   // 524288 quads
#define WQ  (DI*DM/4)     // 32768
#define WXQ (48*DI/4)     // 6144
__global__ __launch_bounds__(256) void k_cvt(const float* __restrict__ x,
                                             const float* __restrict__ Win,
                                             const float* __restrict__ Wx,
                                             unsigned short* __restrict__ xb,
                                             unsigned short* __restrict__ wb,
                                             unsigned short* __restrict__ wxb) {
    int i = blockIdx.x * 256 + threadIdx.x;
    if (i < XQ) {
        float4 v = ((const float4*)x)[i];
        ushort4 o = { rne_bf16(v.x), rne_bf16(v.y), rne_bf16(v.z), rne_bf16(v.w) };
        ((ushort4*)xb)[i] = o;
    } else if (i < XQ + WQ) {
        int j = i - XQ;
        float4 v = ((const float4*)Win)[j];
        ushort4 o = { rne_bf16(v.x), rne_bf16(v.y), rne_bf16(v.z), rne_bf16(v.w) };
        ((ushort4*)wb)[j] = o;
    } else if (i < XQ + WQ + WXQ) {
        int j = i - XQ - WQ;
        float4 v = ((const float4*)Wx)[j];
        ushort4 o = { rne_bf16(v.x), rne_bf16(v.y), rne_bf16(v.z), rne_bf16(v.w) };
        ((ushort4*)wxb)[j] = o;
    }
}

// ---------------- K1: xi = x @ W_in[0:512]^T via bf16 MFMA ----------------
__global__ __launch_bounds__(256) void k_gemm_mfma(const unsigned short* __restrict__ xb,
                                                   const unsigned short* __restrict__ wb,
                                                   float* __restrict__ xi) {
    __shared__ unsigned short As[64][136];
    __shared__ unsigned short Bs[64][136];
    const int tid = threadIdx.x;
    const int m0 = blockIdx.x * 64, n0 = blockIdx.y * 64;
    const int lane = tid & 63, wid = tid >> 6;
    const int mrow = (wid << 4) + (lane & 15);
    const int quad = lane >> 4;
    f4v acc[4] = {{0,0,0,0},{0,0,0,0},{0,0,0,0},{0,0,0,0}};
    for (int kh = 0; kh < DM; kh += 128) {
        __syncthreads();
#pragma unroll
        for (int i = tid; i < 64*16; i += 256) {
            int r = i >> 4, c8 = (i & 15) << 3;
            *(uint4*)&As[r][c8] = *(const uint4*)(xb + (size_t)(m0+r)*DM + kh + c8);
            *(uint4*)&Bs[r][c8] = *(const uint4*)(wb + (size_t)(n0+r)*DM + kh + c8);
        }
        __syncthreads();
#pragma unroll
        for (int ks = 0; ks < 128; ks += 32) {
            s8v a = *(const s8v*)&As[mrow][ks + quad*8];
#pragma unroll
            for (int nt = 0; nt < 4; ++nt) {
                s8v b = *(const s8v*)&Bs[(nt<<4) + (lane & 15)][ks + quad*8];
                acc[nt] = __builtin_amdgcn_mfma_f32_16x16x32_bf16(a, b, acc[nt], 0, 0, 0);
            }
        }
    }
    const int col = lane & 15;
    const int rbase = m0 + (wid << 4) + (quad << 2);
#pragma unroll
    for (int nt = 0; nt < 4; ++nt)
#pragma unroll
        for (int r = 0; r < 4; ++r)
            xi[(size_t)(rbase + r) * DI + n0 + (nt<<4) + col] = acc[nt][r];
}

// ---------------- K1b: z_last[b,d] = x[b,L-1,:] . W_in[512+d,:] ----------------
__global__ __launch_bounds__(256) void k_zlast(const float* __restrict__ x,
                                               const float* __restrict__ Win,
                                               float* __restrict__ zl) {
    int sub = threadIdx.x & 15;
    int idx = blockIdx.x * 16 + (threadIdx.x >> 4);   // 0..2047
    int b = idx >> 9, d = idx & (DI-1);
    const float* xr = x + (size_t)(b*LL + LL-1) * DM + sub*16;
    const float* wr = Win + (size_t)(DI + d) * DM + sub*16;
    float acc = 0.f;
#pragma unroll
    for (int k = 0; k < 16; k += 4)
        acc = dot4(*(const float4*)(xr+k), *(const float4*)(wr+k), acc);
    acc += __shfl_xor(acc, 1); acc += __shfl_xor(acc, 2);
    acc += __shfl_xor(acc, 4); acc += __shfl_xor(acc, 8);
    if (sub == 0) zl[idx] = acc;
}

// ---------------- K2: causal depthwise conv (k=4) + SiLU -> xs (fp32 + bf16) ----------------
__global__ void k_conv(const float* __restrict__ xi, const float* __restrict__ cw,
                       const float* __restrict__ cb, float* __restrict__ xs,
                       unsigned short* __restrict__ xsb) {
    int idx = blockIdx.x * 256 + threadIdx.x;   // over ROWS*DI
    int d = idx & (DI-1);
    int r = idx >> 9;          // b*LL + l
    int l = r & (LL-1);
    float4 w = *(const float4*)(cw + d*4);
    float acc = cb[d];
    if (l >= 3) {
        acc = fmaf(w.x, xi[(size_t)(r-3)*DI + d], acc);
        acc = fmaf(w.y, xi[(size_t)(r-2)*DI + d], acc);
        acc = fmaf(w.z, xi[(size_t)(r-1)*DI + d], acc);
        acc = fmaf(w.w, xi[(size_t)(r  )*DI + d], acc);
    } else {
        const float wk[4] = {w.x, w.y, w.z, w.w};
#pragma unroll
        for (int k = 0; k < 4; ++k) {
            int lt = l - 3 + k;
            if (lt >= 0) acc = fmaf(wk[k], xi[(size_t)(r-3+k)*DI + d], acc);
        }
    }
    float v = acc * sig_(acc);   // silu
    xs[idx] = v;
    xsb[idx] = rne_bf16(v);
}

// ---------------- K3: proj = xs @ W_xproj^T via bf16 MFMA (whole Wx in LDS) ----------------
__global__ __launch_bounds__(256) void k_proj_mfma(const unsigned short* __restrict__ xsb,
                                                   const unsigned short* __restrict__ wxb,
                                                   float* __restrict__ proj) {
    __shared__ unsigned short Bs[48][520];   // all of Wx: 48 x 512 bf16
    __shared__ unsigned short As[64][136];
    const int tid = threadIdx.x;
    const int m0 = blockIdx.x * 64;
    const int lane = tid & 63, wid = tid >> 6;
    const int nrow = lane & 15;
    const int quad = lane >> 4;
#pragma unroll
    for (int i = tid; i < 3072; i += 256) {    // stage B once
        int e = i >> 6, c8 = (i & 63) << 3;
        *(uint4*)&Bs[e][c8] = *(const uint4*)(wxb + (size_t)e*DI + c8);
    }
    f4v acc[3] = {{0,0,0,0},{0,0,0,0},{0,0,0,0}};
    for (int kh = 0; kh < DI; kh += 128) {
        __syncthreads();
#pragma unroll
        for (int i = tid; i < 1024; i += 256) {
            int r = i >> 4, c8 = (i & 15) << 3;
            *(uint4*)&As[r][c8] = *(const uint4*)(xsb + (size_t)(m0+r)*DI + kh + c8);
        }
        __syncthreads();
#pragma unroll
        for (int ks = 0; ks < 128; ks += 32) {
            s8v a = *(const s8v*)&As[(wid<<4) + nrow][ks + quad*8];
#pragma unroll
            for (int nt = 0; nt < 3; ++nt) {
                s8v b = *(const s8v*)&Bs[(nt<<4) + nrow][kh + ks + quad*8];
                acc[nt] = __builtin_amdgcn_mfma_f32_16x16x32_bf16(a, b, acc[nt], 0, 0, 0);
            }
        }
    }
    const int rb = m0 + (wid<<4) + (quad<<2);
#pragma unroll
    for (int nt = 0; nt < 3; ++nt)
#pragma unroll
        for (int r = 0; r < 4; ++r)
            proj[(size_t)(rb + r)*48 + (nt<<4) + nrow] = acc[nt][r];
}

// ---------------- K4: dt = softplus(proj[:, :16] @ W_dt^T + b_dt) ----------------
__global__ void k_dt(const float* __restrict__ proj, const float* __restrict__ Wdt,
                     const float* __restrict__ bdt, float* __restrict__ dt) {
    int idx = blockIdx.x * 256 + threadIdx.x;   // over ROWS*DI
    int d = idx & (DI-1);
    int row = idx >> 9;
    const float* pr = proj + (size_t)row * 48;
    const float* wr = Wdt + d * 16;
    float acc = bdt[d];
#pragma unroll
    for (int k = 0; k < 16; k += 4)
        acc = dot4(*(const float4*)(pr+k), *(const float4*)(wr+k), acc);
    dt[idx] = softplus_(acc);
}

// ---------------- K5: per-chunk scan — one thread per (b,c,d), s-loop in regs ----------------
// dt/xs read ONCE. hc layout [b][s][c][d]; Dsum [b][c][d].
__global__ __launch_bounds__(256) void k_scan1(const float* __restrict__ dt,
                                               const float* __restrict__ xs,
                                               const float* __restrict__ proj,
                                               const float* __restrict__ Alog,
                                               float* __restrict__ hc,
                                               float* __restrict__ Dsum) {
    int g = blockIdx.x * 256 + threadIdx.x;   // BB*NC2*DI = 65536
    int d = g & (DI-1);
    int c = (g >> 9) & (NC2-1);
    int b = g >> 14;
    float Af[16];
#pragma unroll
    for (int s4 = 0; s4 < 16; s4 += 4) {
        float4 al = *(const float4*)(Alog + d*16 + s4);
        Af[s4+0] = -__expf(al.x); Af[s4+1] = -__expf(al.y);
        Af[s4+2] = -__expf(al.z); Af[s4+3] = -__expf(al.w);
    }
    float h[16];
#pragma unroll
    for (int s = 0; s < 16; ++s) h[s] = 0.f;
    float Dl = 0.f;
    int rbase = b*LL + c*CK2;
    for (int i = 0; i < CK2; ++i) {
        int r = rbase + i;
        float dtv = dt[(size_t)r*DI + d];               // coalesced, read once
        float xsv = xs[(size_t)r*DI + d];               // coalesced, read once
        float u = dtv * xsv;
        const float* pr = proj + (size_t)r*48 + 16;     // wave-uniform -> scalar loads
        Dl += dtv;
#pragma unroll
        for (int s = 0; s < 16; ++s)
            h[s] = fmaf(__expf(dtv * Af[s]), h[s], u * pr[s]);
    }
#pragma unroll
    for (int s = 0; s < 16; ++s)
        hc[((size_t)((b*16 + s)*NC2 + c) << 9) + d] = h[s];   // coalesced
    Dsum[((size_t)(b*NC2 + c) << 9) + d] = Dl;                 // coalesced
}

// ---------------- K6: cross-chunk combine + y_last epilogue ----------------
__global__ __launch_bounds__(256) void k_scan2(const float* __restrict__ hc,
                                               const float* __restrict__ Dsum,
                                               const float* __restrict__ Alog,
                                               const float* __restrict__ proj,
                                               const float* __restrict__ xs,
                                               const float* __restrict__ Dp,
                                               const float* __restrict__ zl,
                                               float* __restrict__ ypre) {
    int g = blockIdx.x * 256 + threadIdx.x;   // 0..32767
    int s = g & 15;
    int d = (g >> 4) & (DI-1);
    int b = g >> 13;
    float Af = -__expf(Alog[d*DSN + s]);
    const float* hcb = hc + ((size_t)((b*16 + s)*NC2) << 9) + d;   // stride 512 per c
    const float* Db  = Dsum + ((size_t)(b*NC2) << 9) + d;          // stride 512 per c
    float h = 0.f, Ss = 0.f;
#pragma unroll
    for (int c = NC2-1; c >= 0; --c) {
        h = fmaf(__expf(Af * Ss), hcb[(size_t)c << 9], h);
        Ss += Db[(size_t)c << 9];
    }
    int rlast = b*LL + LL - 1;
    float v = h * proj[(size_t)rlast*48 + 32 + s];
    v += __shfl_xor(v, 8);
    v += __shfl_xor(v, 4);
    v += __shfl_xor(v, 2);
    v += __shfl_xor(v, 1);
    if (s == 0) {
        float y = v + xs[(size_t)rlast*DI + d] * Dp[d];
        float z = zl[b*DI + d];
        y *= z * sig_(z);             // * silu(z)
        ypre[b*DI + d] = y;
    }
}

// ---------------- K7: m = y_pre @ W_out^T  (4 x 256, K=512) ----------------
__global__ __launch_bounds__(256) void k_mout(const float* __restrict__ ypre,
                                              const float* __restrict__ Wout,
                                              float* __restrict__ m) {
    int sub = threadIdx.x & 15;
    int idx = blockIdx.x * 16 + (threadIdx.x >> 4);   // 0..1023
    int b = idx >> 8, o = idx & 255;
    const float* yr = ypre + b * DI + sub*32;
    const float* wr = Wout + (size_t)o * DI + sub*32;
    float acc = 0.f;
#pragma unroll
    for (int k = 0; k < 32; k += 4)
        acc = dot4(*(const float4*)(yr+k), *(const float4*)(wr+k), acc);
    acc += __shfl_xor(acc, 1); acc += __shfl_xor(acc, 2);
    acc += __shfl_xor(acc, 4); acc += __shfl_xor(acc, 8);
    if (sub == 0) m[idx] = acc;
}

// ---------------- K8: LSTM cell — one wave per (b,j) ----------------
__global__ __launch_bounds__(256) void k_lstm(const float* __restrict__ m,
                                              const float* __restrict__ h0,
                                              const float* __restrict__ c0,
                                              const float* __restrict__ Wih,
                                              const float* __restrict__ Whh,
                                              const float* __restrict__ bih,
                                              const float* __restrict__ bhh,
                                              float* __restrict__ out) {
    int lane = threadIdx.x & 63;
    int wid  = threadIdx.x >> 6;
    int p = blockIdx.x * 4 + wid;     // 0..2047
    int b = p >> 9, j = p & (HIDN-1);
    int q = lane >> 4, sub = lane & 15;
    int jj = q * HIDN + j;
    float acc = 0.f;
    {
        const float* wi = Wih + (size_t)jj * DM + sub*16;
        const float* mr = m + b * DM + sub*16;
#pragma unroll
        for (int k = 0; k < 16; k += 4)
            acc = dot4(*(const float4*)(mr+k), *(const float4*)(wi+k), acc);
    }
    {
        const float* wh = Whh + (size_t)jj * HIDN + sub*32;
        const float* hr = h0 + b * HIDN + sub*32;
#pragma unroll
        for (int k = 0; k < 32; k += 4)
            acc = dot4(*(const float4*)(hr+k), *(const float4*)(wh+k), acc);
    }
    if (sub == 0) acc += bih[jj] + bhh[jj];
    acc += __shfl_xor(acc, 1); acc += __shfl_xor(acc, 2);
    acc += __shfl_xor(acc, 4); acc += __shfl_xor(acc, 8);
    float gi = __shfl(acc, 0);
    float gf = __shfl(acc, 16);
    float gg = __shfl(acc, 32);
    float go = __shfl(acc, 48);
    if (lane == 0) {
        int idx = b * HIDN + j;
        float cn = sig_(gf) * c0[idx] + sig_(gi) * tanhf(gg);
        float hn = sig_(go) * tanhf(cn);
        out[idx] = hn;                 // h_new
        out[BB*HIDN + idx] = cn;       // c_new
    }
}

extern "C" void kernel_launch(void* const* d_in, const int* in_sizes, int n_in,
                              void* d_out, int out_size, void* d_ws, size_t ws_size,
                              hipStream_t stream) {
    const float* x     = (const float*)d_in[0];
    const float* h0    = (const float*)d_in[1];
    const float* c0    = (const float*)d_in[2];
    const float* Win   = (const float*)d_in[3];
    const float* convw = (const float*)d_in[4];
    const float* convb = (const float*)d_in[5];
    const float* Wx    = (const float*)d_in[6];
    const float* Wdt   = (const float*)d_in[7];
    const float* bdt   = (const float*)d_in[8];
    const float* Alog  = (const float*)d_in[9];
    const float* Dp    = (const float*)d_in[10];
    const float* Wout  = (const float*)d_in[11];
    const float* Wih   = (const float*)d_in[12];
    const float* Whh   = (const float*)d_in[13];
    const float* bih   = (const float*)d_in[14];
    const float* bhh   = (const float*)d_in[15];

    float* ws   = (float*)d_ws;
    float* xi   = ws;                         // ROWS*DI  (reused as dt buffer)
    float* xs   = xi + (size_t)ROWS*DI;       // ROWS*DI
    float* proj = xs + (size_t)ROWS*DI;       // ROWS*48
    float* hc   = proj + (size_t)ROWS*48;     // BB*16*NC2*DI = 1048576  [b][s][c][d]
    float* Dsum = hc + (size_t)BB*DSN*NC2*DI; // BB*NC2*DI = 65536       [b][c][d]
    float* zl   = Dsum + (size_t)BB*NC2*DI;   // BB*DI
    float* ypre = zl + (size_t)BB*DI;         // BB*DI
    float* mm   = ypre + (size_t)BB*DI;       // BB*DM
    unsigned short* xb  = (unsigned short*)(mm + (size_t)BB*DM);  // ROWS*DM bf16
    unsigned short* wb  = xb + (size_t)ROWS*DM;                   // DI*DM bf16
    unsigned short* wxb = wb + (size_t)DI*DM;                     // 48*DI bf16
    unsigned short* xsb = wxb + (size_t)48*DI;                    // ROWS*DI bf16
    float* out  = (float*)d_out;

    k_cvt      <<<(XQ+WQ+WXQ+255)/256, 256, 0, stream>>>(x, Win, Wx, xb, wb, wxb);
    k_gemm_mfma<<<dim3(ROWS/64, DI/64), 256, 0, stream>>>(xb, wb, xi);
    k_zlast    <<<BB*DI/16, 256, 0, stream>>>(x, Win, zl);
    k_conv     <<<(size_t)ROWS*DI/256, 256, 0, stream>>>(xi, convw, convb, xs, xsb);
    k_proj_mfma<<<ROWS/64, 256, 0, stream>>>(xsb, wxb, proj);
    k_dt       <<<(size_t)ROWS*DI/256, 256, 0, stream>>>(proj, Wdt, bdt, xi /*dt*/);
    k_scan1    <<<BB*NC2*DI/256, 256, 0, stream>>>(xi, xs, proj, Alog, hc, Dsum);
    k_scan2    <<<BB*DI*DSN/256, 256, 0, stream>>>(hc, Dsum, Alog, proj, xs, Dp, zl, ypre);
    k_mout     <<<BB*DM/16, 256, 0, stream>>>(ypre, Wout, mm);
    k_lstm     <<<BB*HIDN/4, 256, 0, stream>>>(mm, h0, c0, Wih, Whh, bih, bhh, out);
}

// Round 7
// 189.639 us; speedup vs baseline: 1.0786x; 1.0786x over previous
//
#include <hip/hip_runtime.h>
#include <math.h>

#define BB   4
#define LL   2048
#define DM   256
#define DI   512
#define DSN  16
#define HIDN 512
#define NC   64
#define CK   32           // LL / NC
#define ROWS (BB*LL)      // 8192

typedef __attribute__((ext_vector_type(8))) short s8v;   // 8 bf16 (4 VGPRs)
typedef __attribute__((ext_vector_type(4))) float f4v;   // 4 fp32 acc

__device__ __forceinline__ float sig_(float x) { return 1.f / (1.f + __expf(-x)); }
__device__ __forceinline__ float dot4(float4 a, float4 w, float acc) {
    return fmaf(a.x,w.x, fmaf(a.y,w.y, fmaf(a.z,w.z, fmaf(a.w,w.w, acc))));
}
__device__ __forceinline__ unsigned short rne_bf16(float f) {
    union { float f; unsigned u; } v; v.f = f;
    unsigned r = v.u + 0x7FFFu + ((v.u >> 16) & 1u);
    return (unsigned short)(r >> 16);
}
__device__ __forceinline__ float softplus_(float a) {
    return (a > 15.f) ? a : __logf(1.f + __expf(a));
}

// ---------------- K_A: zlast (blocks 0..127) + Wx->bf16 cvt (blocks 128..151) ----------------
#define WXQ (48*DI/4)     // 6144 quads
__global__ __launch_bounds__(256) void k_misc(const float* __restrict__ x,
                                              const float* __restrict__ Win,
                                              const float* __restrict__ Wx,
                                              float* __restrict__ zl,
                                              unsigned short* __restrict__ wxb) {
    if (blockIdx.x < 128) {
        int sub = threadIdx.x & 15;
        int idx = blockIdx.x * 16 + (threadIdx.x >> 4);   // 0..2047
        int b = idx >> 9, d = idx & (DI-1);
        const float* xr = x + (size_t)(b*LL + LL-1) * DM + sub*16;
        const float* wr = Win + (size_t)(DI + d) * DM + sub*16;
        float acc = 0.f;
#pragma unroll
        for (int k = 0; k < 16; k += 4)
            acc = dot4(*(const float4*)(xr+k), *(const float4*)(wr+k), acc);
        acc += __shfl_xor(acc, 1); acc += __shfl_xor(acc, 2);
        acc += __shfl_xor(acc, 4); acc += __shfl_xor(acc, 8);
        if (sub == 0) zl[idx] = acc;
    } else {
        int i = (blockIdx.x - 128) * 256 + threadIdx.x;   // 0..6143
        float4 v = ((const float4*)Wx)[i];
        ushort4 o = { rne_bf16(v.x), rne_bf16(v.y), rne_bf16(v.z), rne_bf16(v.w) };
        ((ushort4*)wxb)[i] = o;
    }
}

// ---------------- K_B: fused [cvt + xi-GEMM(MFMA) + causal conv + SiLU] ----------------
// A-tile 80 rows (16 halo) x 64 cols; conv runs from LDS xi tile; xi never hits HBM.
__global__ __launch_bounds__(256) void k_gemm_conv(const float* __restrict__ x,
                                                   const float* __restrict__ Win,
                                                   const float* __restrict__ cw,
                                                   const float* __restrict__ cb,
                                                   float* __restrict__ xs,
                                                   unsigned short* __restrict__ xsb) {
    __shared__ __align__(16) char smem[39168];   // As 80x136 bf16 | Bs 64x136 bf16
    unsigned short (*As)[136] = (unsigned short (*)[136])smem;
    unsigned short (*Bs)[136] = (unsigned short (*)[136])(smem + 21760);
    float (*xiL)[68] = (float (*)[68])smem;      // aliases As after compute (21760 B)

    const int tid = threadIdx.x;
    const int m0 = blockIdx.x * 64, n0 = blockIdx.y * 64;
    const int lane = tid & 63, wid = tid >> 6;
    const int quad = lane >> 4, l15 = lane & 15;

    f4v acc[4] = {{0,0,0,0},{0,0,0,0},{0,0,0,0},{0,0,0,0}};
    f4v hacc[4] = {{0,0,0,0},{0,0,0,0},{0,0,0,0},{0,0,0,0}};   // halo (wave 0 only)

    for (int kh = 0; kh < DM; kh += 128) {
        __syncthreads();
        // stage A: rows m0-16 .. m0+63 (clamped), cols kh..kh+128, fp32->bf16 inline
#pragma unroll
        for (int i = tid; i < 80*32; i += 256) {
            int r = i >> 5, c4 = (i & 31) << 2;
            int gr = m0 - 16 + r; if (gr < 0) gr = 0;
            float4 v = *(const float4*)(x + (size_t)gr * DM + kh + c4);
            ushort4 o = { rne_bf16(v.x), rne_bf16(v.y), rne_bf16(v.z), rne_bf16(v.w) };
            *(ushort4*)&As[r][c4] = o;
        }
        // stage B: Win rows n0..n0+63
#pragma unroll
        for (int i = tid; i < 64*32; i += 256) {
            int r = i >> 5, c4 = (i & 31) << 2;
            float4 v = *(const float4*)(Win + (size_t)(n0 + r) * DM + kh + c4);
            ushort4 o = { rne_bf16(v.x), rne_bf16(v.y), rne_bf16(v.z), rne_bf16(v.w) };
            *(ushort4*)&Bs[r][c4] = o;
        }
        __syncthreads();
#pragma unroll
        for (int ks = 0; ks < 128; ks += 32) {
            s8v a = *(const s8v*)&As[16 + (wid<<4) + l15][ks + quad*8];
#pragma unroll
            for (int nt = 0; nt < 4; ++nt) {
                s8v b = *(const s8v*)&Bs[(nt<<4) + l15][ks + quad*8];
                acc[nt] = __builtin_amdgcn_mfma_f32_16x16x32_bf16(a, b, acc[nt], 0, 0, 0);
            }
            if (wid == 0) {
                s8v ah = *(const s8v*)&As[l15][ks + quad*8];
#pragma unroll
                for (int nt = 0; nt < 4; ++nt) {
                    s8v b = *(const s8v*)&Bs[(nt<<4) + l15][ks + quad*8];
                    hacc[nt] = __builtin_amdgcn_mfma_f32_16x16x32_bf16(ah, b, hacc[nt], 0, 0, 0);
                }
            }
        }
    }
    __syncthreads();   // done reading As/Bs; reuse as xiL
    {
        const int rb = 16 + (wid<<4) + (quad<<2);
#pragma unroll
        for (int nt = 0; nt < 4; ++nt)
#pragma unroll
            for (int r = 0; r < 4; ++r)
                xiL[rb + r][(nt<<4) + l15] = acc[nt][r];
        if (wid == 0) {
#pragma unroll
            for (int nt = 0; nt < 4; ++nt)
#pragma unroll
                for (int r = 0; r < 4; ++r)
                    xiL[(quad<<2) + r][(nt<<4) + l15] = hacc[nt][r];
        }
    }
    __syncthreads();
    // conv + silu from LDS xi tile: thread -> col c, 16 rows
    {
        const int c = tid & 63, rg = tid >> 6;
        const int d = n0 + c;
        float4 w = *(const float4*)(cw + d*4);
        const float wk[4] = {w.x, w.y, w.z, w.w};
        float bias = cb[d];
#pragma unroll
        for (int rr = 0; rr < 16; ++rr) {
            int orow = (rg << 4) + rr;        // 0..63
            int Lr = 16 + orow;
            int l = (m0 + orow) & (LL-1);
            float a = bias;
            if (l >= 3) {
                a = fmaf(wk[0], xiL[Lr-3][c], a);
                a = fmaf(wk[1], xiL[Lr-2][c], a);
                a = fmaf(wk[2], xiL[Lr-1][c], a);
                a = fmaf(wk[3], xiL[Lr  ][c], a);
            } else {
#pragma unroll
                for (int k = 0; k < 4; ++k) {
                    int lt = l - 3 + k;
                    if (lt >= 0) a = fmaf(wk[k], xiL[Lr-3+k][c], a);
                }
            }
            float v = a * sig_(a);
            size_t gi = (size_t)(m0 + orow) * DI + d;
            xs[gi] = v;
            xsb[gi] = rne_bf16(v);
        }
    }
}

// ---------------- K_C: proj = xs @ W_xproj^T via bf16 MFMA (whole Wx in LDS) ----------------
__global__ __launch_bounds__(256) void k_proj_mfma(const unsigned short* __restrict__ xsb,
                                                   const unsigned short* __restrict__ wxb,
                                                   float* __restrict__ proj) {
    __shared__ unsigned short Bs[48][520];
    __shared__ unsigned short As[64][136];
    const int tid = threadIdx.x;
    const int m0 = blockIdx.x * 64;
    const int lane = tid & 63, wid = tid >> 6;
    const int nrow = lane & 15;
    const int quad = lane >> 4;
#pragma unroll
    for (int i = tid; i < 3072; i += 256) {
        int e = i >> 6, c8 = (i & 63) << 3;
        *(uint4*)&Bs[e][c8] = *(const uint4*)(wxb + (size_t)e*DI + c8);
    }
    f4v acc[3] = {{0,0,0,0},{0,0,0,0},{0,0,0,0}};
    for (int kh = 0; kh < DI; kh += 128) {
        __syncthreads();
#pragma unroll
        for (int i = tid; i < 1024; i += 256) {
            int r = i >> 4, c8 = (i & 15) << 3;
            *(uint4*)&As[r][c8] = *(const uint4*)(xsb + (size_t)(m0+r)*DI + kh + c8);
        }
        __syncthreads();
#pragma unroll
        for (int ks = 0; ks < 128; ks += 32) {
            s8v a = *(const s8v*)&As[(wid<<4) + nrow][ks + quad*8];
#pragma unroll
            for (int nt = 0; nt < 3; ++nt) {
                s8v b = *(const s8v*)&Bs[(nt<<4) + nrow][kh + ks + quad*8];
                acc[nt] = __builtin_amdgcn_mfma_f32_16x16x32_bf16(a, b, acc[nt], 0, 0, 0);
            }
        }
    }
    const int rb = m0 + (wid<<4) + (quad<<2);
#pragma unroll
    for (int nt = 0; nt < 3; ++nt)
#pragma unroll
        for (int r = 0; r < 4; ++r)
            proj[(size_t)(rb + r)*48 + (nt<<4) + nrow] = acc[nt][r];
}

// ---------------- K_D: scan1 with inline dt — thread per (b,c,d), s in regs ----------------
// hc layout [b][s][c][d]; Dsum [b][c][d]
__global__ __launch_bounds__(256) void k_scan1(const float* __restrict__ xs,
                                               const float* __restrict__ proj,
                                               const float* __restrict__ Wdt,
                                               const float* __restrict__ bdt,
                                               const float* __restrict__ Alog,
                                               float* __restrict__ hc,
                                               float* __restrict__ Dsum) {
    int g = blockIdx.x * 256 + threadIdx.x;   // BB*NC*DI = 131072
    int d = g & (DI-1);
    int c = (g >> 9) & (NC-1);
    int b = g >> 15;
    float wdt[16];
#pragma unroll
    for (int e = 0; e < 16; e += 4) {
        float4 v = *(const float4*)(Wdt + d*16 + e);
        wdt[e]=v.x; wdt[e+1]=v.y; wdt[e+2]=v.z; wdt[e+3]=v.w;
    }
    float bd = bdt[d];
    float Af[16];
#pragma unroll
    for (int s4 = 0; s4 < 16; s4 += 4) {
        float4 al = *(const float4*)(Alog + d*16 + s4);
        Af[s4+0] = -__expf(al.x); Af[s4+1] = -__expf(al.y);
        Af[s4+2] = -__expf(al.z); Af[s4+3] = -__expf(al.w);
    }
    float h[16];
#pragma unroll
    for (int s = 0; s < 16; ++s) h[s] = 0.f;
    float Dl = 0.f;
    int rbase = b*LL + c*CK;
    for (int i = 0; i < CK; ++i) {
        int r = rbase + i;
        const float* pr = proj + (size_t)r*48;          // wave-uniform -> scalar loads
        float a = bd;
#pragma unroll
        for (int e = 0; e < 16; ++e) a = fmaf(pr[e], wdt[e], a);
        float dtv = softplus_(a);
        float xsv = xs[(size_t)r*DI + d];               // coalesced
        float u = dtv * xsv;
        Dl += dtv;
#pragma unroll
        for (int s = 0; s < 16; ++s)
            h[s] = fmaf(__expf(dtv * Af[s]), h[s], u * pr[16+s]);
    }
#pragma unroll
    for (int s = 0; s < 16; ++s)
        hc[((size_t)((b*16 + s)*NC + c) << 9) + d] = h[s];
    Dsum[((size_t)(b*NC + c) << 9) + d] = Dl;
}

// ---------------- K_E: scan2 — thread per (b,d), s in regs, fused epilogue ----------------
__global__ __launch_bounds__(128) void k_scan2(const float* __restrict__ hc,
                                               const float* __restrict__ Dsum,
                                               const float* __restrict__ Alog,
                                               const float* __restrict__ proj,
                                               const float* __restrict__ xs,
                                               const float* __restrict__ Dp,
                                               const float* __restrict__ zl,
                                               float* __restrict__ ypre) {
    int b = blockIdx.x >> 2;
    int d = ((blockIdx.x & 3) << 7) + threadIdx.x;   // 0..511
    float Af[16];
#pragma unroll
    for (int s4 = 0; s4 < 16; s4 += 4) {
        float4 al = *(const float4*)(Alog + d*16 + s4);
        Af[s4+0] = -__expf(al.x); Af[s4+1] = -__expf(al.y);
        Af[s4+2] = -__expf(al.z); Af[s4+3] = -__expf(al.w);
    }
    float h[16];
#pragma unroll
    for (int s = 0; s < 16; ++s) h[s] = 0.f;
    float Ss = 0.f;
    const float* hcb = hc + ((size_t)(b*16*NC) << 9) + d;
    const float* Db  = Dsum + ((size_t)(b*NC) << 9) + d;
    for (int c = NC-1; c >= 0; --c) {
        float Dc = Db[(size_t)c << 9];
#pragma unroll
        for (int s = 0; s < 16; ++s)
            h[s] = fmaf(__expf(Af[s] * Ss), hcb[((size_t)(s*NC + c)) << 9], h[s]);
        Ss += Dc;
    }
    int rlast = b*LL + LL - 1;
    const float* pr = proj + (size_t)rlast*48 + 32;   // wave-uniform
    float y = 0.f;
#pragma unroll
    for (int s = 0; s < 16; ++s) y = fmaf(h[s], pr[s], y);
    y += xs[(size_t)rlast*DI + d] * Dp[d];
    float z = zl[b*DI + d];
    y *= z * sig_(z);
    ypre[b*DI + d] = y;
}

// ---------------- K_F: m = y_pre @ W_out^T  (4 x 256, K=512) ----------------
__global__ __launch_bounds__(256) void k_mout(const float* __restrict__ ypre,
                                              const float* __restrict__ Wout,
                                              float* __restrict__ m) {
    int sub = threadIdx.x & 15;
    int idx = blockIdx.x * 16 + (threadIdx.x >> 4);   // 0..1023
    int b = idx >> 8, o = idx & 255;
    const float* yr = ypre + b * DI + sub*32;
    const float* wr = Wout + (size_t)o * DI + sub*32;
    float acc = 0.f;
#pragma unroll
    for (int k = 0; k < 32; k += 4)
        acc = dot4(*(const float4*)(yr+k), *(const float4*)(wr+k), acc);
    acc += __shfl_xor(acc, 1); acc += __shfl_xor(acc, 2);
    acc += __shfl_xor(acc, 4); acc += __shfl_xor(acc, 8);
    if (sub == 0) m[idx] = acc;
}

// ---------------- K_G: LSTM cell — one wave per (b,j) ----------------
__global__ __launch_bounds__(256) void k_lstm(const float* __restrict__ m,
                                              const float* __restrict__ h0,
                                              const float* __restrict__ c0,
                                              const float* __restrict__ Wih,
                                              const float* __restrict__ Whh,
                                              const float* __restrict__ bih,
                                              const float* __restrict__ bhh,
                                              float* __restrict__ out) {
    int lane = threadIdx.x & 63;
    int wid  = threadIdx.x >> 6;
    int p = blockIdx.x * 4 + wid;     // 0..2047
    int b = p >> 9, j = p & (HIDN-1);
    int q = lane >> 4, sub = lane & 15;
    int jj = q * HIDN + j;
    float acc = 0.f;
    {
        const float* wi = Wih + (size_t)jj * DM + sub*16;
        const float* mr = m + b * DM + sub*16;
#pragma unroll
        for (int k = 0; k < 16; k += 4)
            acc = dot4(*(const float4*)(mr+k), *(const float4*)(wi+k), acc);
    }
    {
        const float* wh = Whh + (size_t)jj * HIDN + sub*32;
        const float* hr = h0 + b * HIDN + sub*32;
#pragma unroll
        for (int k = 0; k < 32; k += 4)
            acc = dot4(*(const float4*)(hr+k), *(const float4*)(wh+k), acc);
    }
    if (sub == 0) acc += bih[jj] + bhh[jj];
    acc += __shfl_xor(acc, 1); acc += __shfl_xor(acc, 2);
    acc += __shfl_xor(acc, 4); acc += __shfl_xor(acc, 8);
    float gi = __shfl(acc, 0);
    float gf = __shfl(acc, 16);
    float gg = __shfl(acc, 32);
    float go = __shfl(acc, 48);
    if (lane == 0) {
        int idx = b * HIDN + j;
        float cn = sig_(gf) * c0[idx] + sig_(gi) * tanhf(gg);
        float hn = sig_(go) * tanhf(cn);
        out[idx] = hn;                 // h_new
        out[BB*HIDN + idx] = cn;       // c_new
    }
}

extern "C" void kernel_launch(void* const* d_in, const int* in_sizes, int n_in,
                              void* d_out, int out_size, void* d_ws, size_t ws_size,
                              hipStream_t stream) {
    const float* x     = (const float*)d_in[0];
    const float* h0    = (const float*)d_in[1];
    const float* c0    = (const float*)d_in[2];
    const float* Win   = (const float*)d_in[3];
    const float* convw = (const float*)d_in[4];
    const float* convb = (const float*)d_in[5];
    const float* Wx    = (const float*)d_in[6];
    const float* Wdt   = (const float*)d_in[7];
    const float* bdt   = (const float*)d_in[8];
    const float* Alog  = (const float*)d_in[9];
    const float* Dp    = (const float*)d_in[10];
    const float* Wout  = (const float*)d_in[11];
    const float* Wih   = (const float*)d_in[12];
    const float* Whh   = (const float*)d_in[13];
    const float* bih   = (const float*)d_in[14];
    const float* bhh   = (const float*)d_in[15];

    float* ws   = (float*)d_ws;
    float* xs   = ws;                          // ROWS*DI
    float* proj = xs + (size_t)ROWS*DI;        // ROWS*48
    float* hc   = proj + (size_t)ROWS*48;      // BB*16*NC*DI = 2097152  [b][s][c][d]
    float* Dsum = hc + (size_t)BB*DSN*NC*DI;   // BB*NC*DI = 131072      [b][c][d]
    float* zl   = Dsum + (size_t)BB*NC*DI;     // BB*DI
    float* ypre = zl + (size_t)BB*DI;          // BB*DI
    float* mm   = ypre + (size_t)BB*DI;        // BB*DM
    unsigned short* wxb = (unsigned short*)(mm + (size_t)BB*DM);  // 48*DI bf16
    unsigned short* xsb = wxb + (size_t)48*DI;                    // ROWS*DI bf16
    float* out  = (float*)d_out;

    k_misc     <<<152, 256, 0, stream>>>(x, Win, Wx, zl, wxb);
    k_gemm_conv<<<dim3(ROWS/64, DI/64), 256, 0, stream>>>(x, Win, convw, convb, xs, xsb);
    k_proj_mfma<<<ROWS/64, 256, 0, stream>>>(xsb, wxb, proj);
    k_scan1    <<<BB*NC*DI/256, 256, 0, stream>>>(xs, proj, Wdt, bdt, Alog, hc, Dsum);
    k_scan2    <<<16, 128, 0, stream>>>(hc, Dsum, Alog, proj, xs, Dp, zl, ypre);
    k_mout     <<<BB*DM/16, 256, 0, stream>>>(ypre, Wout, mm);
    k_lstm     <<<BB*HIDN/4, 256, 0, stream>>>(mm, h0, c0, Wih, Whh, bih, bhh, out);
}